// Round 1
// baseline (356.642 us; speedup 1.0000x reference)
//
#include <hip/hip_runtime.h>
#include <hip/hip_bf16.h>

// Problem constants
static constexpr int Bn = 8, Cn = 128, Hn = 64, Wn = 64, Con = 128;
static constexpr int KKn = 9, DGn = 2, Cgn = 64;
static constexpr int HOn = 64, WOn = 64;

// ---------------------------------------------------------------------------
// Kernel 0: transpose main weight [Co,C,3,3] -> wt[gk][c][oc] (gk = g*9+k)
// so main-kernel LDS staging reads are fully coalesced.
// 18*64*128 = 147456 elements, grid 576 x 256.
// ---------------------------------------------------------------------------
__global__ __launch_bounds__(256) void wt_transpose(const float* __restrict__ w,
                                                    float* __restrict__ wt) {
    int e  = blockIdx.x * 256 + threadIdx.x;     // [0, 147456)
    int oc = e & 127;
    int c  = (e >> 7) & 63;
    int gk = e >> 13;                            // 0..17
    int g  = gk / 9, k = gk - g * 9;
    wt[e] = w[((size_t)oc * Cn + g * Cgn + c) * KKn + k];
}

// ---------------------------------------------------------------------------
// Kernel 1: grouped offset conv (dil=2, pad=2, stride=1), 54 output channels.
// One thread per output element; wo = lane -> weight addresses wave-uniform
// (s_load), x loads coalesced along wo.
// grid (16, 54, 8), block 256 (4 ho-rows per block).
// ---------------------------------------------------------------------------
__global__ __launch_bounds__(256) void offset_conv(const float* __restrict__ x,
                                                   const float* __restrict__ ow,
                                                   const float* __restrict__ ob,
                                                   float* __restrict__ om) {
    const int t  = threadIdx.x;
    const int wo = t & 63;
    const int ho = blockIdx.x * 4 + (t >> 6);
    const int oc = blockIdx.y;                   // 0..53
    const int b  = blockIdx.z;
    const int g  = oc / 27;

    const float* xb = x + ((size_t)b * Cn + g * Cgn) * (Hn * Wn);
    const float* wb = ow + (size_t)oc * Cgn * KKn;

    float acc = ob[oc];
    for (int c = 0; c < Cgn; ++c) {
        const float* xc = xb + (size_t)c * (Hn * Wn);
        const float* wc = wb + c * KKn;
#pragma unroll
        for (int ky = 0; ky < 3; ++ky) {
            int iy = ho - 2 + 2 * ky;
            bool vy = (iy >= 0) & (iy < Hn);
#pragma unroll
            for (int kx = 0; kx < 3; ++kx) {
                int ix = wo - 2 + 2 * kx;
                bool v = vy & (ix >= 0) & (ix < Wn);
                float xv = v ? xc[iy * Wn + ix] : 0.f;
                acc = fmaf(xv, wc[ky * 3 + kx], acc);
            }
        }
    }
    om[(((size_t)b * 54 + oc) * HOn + ho) * WOn + wo] = acc;
}

// ---------------------------------------------------------------------------
// Kernel 2: fused deformable gather + dense contraction.
// One block per (b, ho) row: 64 output positions x 128 output channels.
// Per (g,k): gather val[64c][64pos] tile into LDS (corner weights premultiplied
// by 2*sigmoid(mask), invalid corners zeroed), stage w[64c][128oc] slab,
// register-blocked fp32 GEMM (4 pos x 8 oc per thread).
// LDS: 32768 (w) + 16384 (val) + 18432 (cw) + 4608 (pk) = 72192 B -> 2 blk/CU.
// ---------------------------------------------------------------------------
__global__ __launch_bounds__(256, 2) void dcn_main(const float* __restrict__ x,
                                                   const float* __restrict__ om,
                                                   const float* __restrict__ wt,
                                                   float* __restrict__ out) {
    __shared__ float  s_w[64][128];
    __shared__ float  s_val[64][64];
    __shared__ float4 s_cw[18][64];
    __shared__ int    s_pk[18][64];

    const int t  = threadIdx.x;
    const int ho = blockIdx.x;
    const int b  = blockIdx.y;

    // ---- sampling params for all (g,k,wo) of this row ----
    for (int e = t; e < 18 * 64; e += 256) {
        int wo = e & 63;
        int gk = e >> 6;                 // 0..17
        int g  = gk / 9, k = gk - g * 9;
        int ky = k / 3,  kx = k - ky * 3;
        const float* omb = om + (size_t)b * 54 * (HOn * WOn) + ho * WOn + wo;
        float offy = omb[(g * 18 + k * 2 + 0) * (HOn * WOn)];
        float offx = omb[(g * 18 + k * 2 + 1) * (HOn * WOn)];
        float mk   = omb[(36 + g * 9 + k) * (HOn * WOn)];
        mk = 2.0f / (1.0f + __expf(-mk));          // double_mask

        float py = offy + (float)(ky * 2 + ho - 2);
        float px = offx + (float)(kx * 2 + wo - 2);
        float fy = floorf(py), fx = floorf(px);
        int   y0 = (int)fy,    x0 = (int)fx;
        float wy = py - fy,    wx = px - fx;

        bool vy0 = (y0 >= 0) & (y0 < Hn);
        bool vy1 = (y0 + 1 >= 0) & (y0 + 1 < Hn);
        bool vx0 = (x0 >= 0) & (x0 < Wn);
        bool vx1 = (x0 + 1 >= 0) & (x0 + 1 < Wn);
        float4 cw;
        cw.x = (vy0 & vx0) ? (1.f - wy) * (1.f - wx) * mk : 0.f;
        cw.y = (vy0 & vx1) ? (1.f - wy) * wx * mk : 0.f;
        cw.z = (vy1 & vx0) ? wy * (1.f - wx) * mk : 0.f;
        cw.w = (vy1 & vx1) ? wy * wx * mk : 0.f;

        int y0c = min(max(y0, 0), Hn - 1);
        int y1c = min(max(y0 + 1, 0), Hn - 1);
        int x0c = min(max(x0, 0), Wn - 1);
        int x1c = min(max(x0 + 1, 0), Wn - 1);
        s_cw[gk][wo] = cw;
        s_pk[gk][wo] = y0c | (y1c << 8) | (x0c << 16) | (x1c << 24);
    }
    __syncthreads();

    float acc[4][8];
#pragma unroll
    for (int p = 0; p < 4; ++p)
#pragma unroll
        for (int j = 0; j < 8; ++j) acc[p][j] = 0.f;

    const int pos = t & 63;   // gather: lane = output position
    const int wv  = t >> 6;   // gather: wave -> channel chunk
    const int tx  = t & 15;   // gemm: pos group (4 positions)
    const int ty  = t >> 4;   // gemm: oc group (8 channels)

    for (int gk = 0; gk < 18; ++gk) {
        if (gk) __syncthreads();
        const int g = gk / 9;

        // ---- gather val tile (each wave: 16 channels for its position) ----
        {
            float4 cw = s_cw[gk][pos];
            int pk = s_pk[gk][pos];
            int y0c = pk & 255, y1c = (pk >> 8) & 255;
            int x0c = (pk >> 16) & 255, x1c = (pk >> 24) & 255;
            int i00 = y0c * Wn + x0c, i01 = y0c * Wn + x1c;
            int i10 = y1c * Wn + x0c, i11 = y1c * Wn + x1c;
            const float* xb = x + ((size_t)(b * Cn + g * Cgn) + wv * 16) * (Hn * Wn);
#pragma unroll 4
            for (int i = 0; i < 16; ++i) {
                const float* xc = xb + (size_t)i * (Hn * Wn);
                float v = cw.x * xc[i00] + cw.y * xc[i01] +
                          cw.z * xc[i10] + cw.w * xc[i11];
                s_val[wv * 16 + i][pos] = v;
            }
        }
        // ---- stage weight slab for this (g,k) ----
        {
            const float4* wsrc = (const float4*)(wt + (size_t)gk * 8192);
            float4* wdst = (float4*)&s_w[0][0];
#pragma unroll
            for (int i = 0; i < 8; ++i) wdst[t + i * 256] = wsrc[t + i * 256];
        }
        __syncthreads();

        // ---- register-blocked GEMM over the 64-channel tile ----
#pragma unroll 8
        for (int c = 0; c < 64; ++c) {
            float4 a  = *(const float4*)&s_val[c][tx * 4];
            float4 b0 = *(const float4*)&s_w[c][ty * 8];
            float4 b1 = *(const float4*)&s_w[c][ty * 8 + 4];
            float av[4] = {a.x, a.y, a.z, a.w};
            float bv[8] = {b0.x, b0.y, b0.z, b0.w, b1.x, b1.y, b1.z, b1.w};
#pragma unroll
            for (int p = 0; p < 4; ++p)
#pragma unroll
                for (int j = 0; j < 8; ++j)
                    acc[p][j] = fmaf(av[p], bv[j], acc[p][j]);
        }
    }

    // ---- store: oc = ty*8+j, wo = tx*4 + p (float4 per oc) ----
#pragma unroll
    for (int j = 0; j < 8; ++j) {
        int oc = ty * 8 + j;
        float4 v = {acc[0][j], acc[1][j], acc[2][j], acc[3][j]};
        *(float4*)(out + (((size_t)b * Con + oc) * HOn + ho) * WOn + tx * 4) = v;
    }
}

// ---------------------------------------------------------------------------
extern "C" void kernel_launch(void* const* d_in, const int* in_sizes, int n_in,
                              void* d_out, int out_size, void* d_ws, size_t ws_size,
                              hipStream_t stream) {
    const float* x  = (const float*)d_in[0];   // [8,128,64,64]
    const float* ow = (const float*)d_in[1];   // [54,64,3,3]
    const float* ob = (const float*)d_in[2];   // [54]
    const float* w  = (const float*)d_in[3];   // [128,128,3,3]
    float* out = (float*)d_out;                // [8,128,64,64]

    // workspace layout: om (8*54*64*64 f32 = 7077888 B) | wt (147456 f32)
    float* om = (float*)d_ws;
    float* wt = (float*)((char*)d_ws + 7077888);

    hipLaunchKernelGGL(wt_transpose, dim3(576), dim3(256), 0, stream, w, wt);
    hipLaunchKernelGGL(offset_conv, dim3(16, 54, 8), dim3(256), 0, stream,
                       x, ow, ob, om);
    hipLaunchKernelGGL(dcn_main, dim3(64, 8), dim3(256), 0, stream,
                       x, om, wt, out);
}